// Round 1
// baseline (4068.305 us; speedup 1.0000x reference)
//
#include <hip/hip_runtime.h>
#include <cstdint>

#define T_STEPS 400
#define B_SZ    256
#define NIN_SZ  64
#define H_SZ    512
#define NOUT_SZ 16
#define NEXC    409          // int(0.8*512) = 409 (not 410!)
#define BTILE   4
#define NBLK    (B_SZ / BTILE)   // 64 workgroups, one per batch-tile
#define NTHR    512

// ---------------------------------------------------------------------------
// Prep: effective weights (Dale's law relu + sign) into workspace.
// ws layout (floats): [0,262144) Wrnn_eff | [262144,294912) Win_eff |
//                     [294912,303104) Wout_eff
// ---------------------------------------------------------------------------
__global__ void prep_weights(const float* __restrict__ W_in,
                             const float* __restrict__ W_rnn,
                             const float* __restrict__ W_out,
                             float* __restrict__ ws) {
    int idx = blockIdx.x * blockDim.x + threadIdx.x;
    const int n_rnn = H_SZ * H_SZ;
    const int n_in  = NIN_SZ * H_SZ;
    const int n_out = H_SZ * NOUT_SZ;
    if (idx < n_rnn) {
        int k = idx >> 9;                      // presynaptic row
        float v = fmaxf(W_rnn[idx], 0.0f);
        ws[idx] = (k < NEXC) ? v : -v;
    } else if (idx < n_rnn + n_in) {
        ws[idx] = fmaxf(W_in[idx - n_rnn], 0.0f);
    } else if (idx < n_rnn + n_in + n_out) {
        ws[idx] = fmaxf(W_out[idx - n_rnn - n_in], 0.0f);
    }
}

#define FMA16(h4, w)                              \
    acc[0][0] = fmaf(h4.x, w.x, acc[0][0]);       \
    acc[0][1] = fmaf(h4.x, w.y, acc[0][1]);       \
    acc[0][2] = fmaf(h4.x, w.z, acc[0][2]);       \
    acc[0][3] = fmaf(h4.x, w.w, acc[0][3]);       \
    acc[1][0] = fmaf(h4.y, w.x, acc[1][0]);       \
    acc[1][1] = fmaf(h4.y, w.y, acc[1][1]);       \
    acc[1][2] = fmaf(h4.y, w.z, acc[1][2]);       \
    acc[1][3] = fmaf(h4.y, w.w, acc[1][3]);       \
    acc[2][0] = fmaf(h4.z, w.x, acc[2][0]);       \
    acc[2][1] = fmaf(h4.z, w.y, acc[2][1]);       \
    acc[2][2] = fmaf(h4.z, w.z, acc[2][2]);       \
    acc[2][3] = fmaf(h4.z, w.w, acc[2][3]);       \
    acc[3][0] = fmaf(h4.w, w.x, acc[3][0]);       \
    acc[3][1] = fmaf(h4.w, w.y, acc[3][1]);       \
    acc[3][2] = fmaf(h4.w, w.z, acc[3][2]);       \
    acc[3][3] = fmaf(h4.w, w.w, acc[3][3]);

// ---------------------------------------------------------------------------
// Persistent sequential kernel. One WG owns BTILE=4 batch rows for all 400
// steps. No inter-WG communication. State: h in LDS (needed by all threads),
// syn_x/syn_u in registers (thread j owns column j for all 4 rows).
// ---------------------------------------------------------------------------
__global__ __launch_bounds__(NTHR)
void biornn_seq(const float* __restrict__ x,
                const float* __restrict__ noise,
                const float* __restrict__ wrnn,   // [512][512] effective
                const float* __restrict__ win,    // [64][512]  effective
                const float* __restrict__ wout,   // [512][16]  effective
                const float* __restrict__ brnn,
                const float* __restrict__ bout,
                float* __restrict__ out_logits,
                float* __restrict__ out_h,
                float* __restrict__ out_sx,
                float* __restrict__ out_su) {
    __shared__ __align__(16) float h_lds[BTILE][H_SZ];      // 8 KB
    __shared__ __align__(16) float hpT[H_SZ][BTILE];        // 8 KB (transposed h_post)
    __shared__ __align__(16) float cbuf[4][BTILE][H_SZ];    // 32 KB (K-split partials)
    __shared__ __align__(16) float xtT[NIN_SZ][BTILE];      // 1 KB (transposed x_t)
    __shared__ float brnn_l[H_SZ];                          // 2 KB
    __shared__ float bout_l[NOUT_SZ];
    __shared__ float pbuf[8][BTILE][NOUT_SZ];               // 2 KB logits partials

    const int tid = threadIdx.x;
    const int b0  = blockIdx.x * BTILE;
    const int j   = tid;                       // owned hidden column

    // per-column STP constants: even j = facilitating, odd j = depressing
    const bool  fac   = ((j & 1) == 0);
    const float Uj    = fac ? 0.15f : 0.45f;
    const float a_stf = fac ? (10.0f / 1500.0f) : (10.0f / 200.0f);
    const float a_std = fac ? (10.0f / 200.0f)  : (10.0f / 1500.0f);

    float sxr[BTILE], sur[BTILE];
#pragma unroll
    for (int r = 0; r < BTILE; ++r) { sxr[r] = 1.0f; sur[r] = Uj; h_lds[r][j] = 0.1f; }
    brnn_l[j] = brnn[j];
    if (tid < NOUT_SZ) bout_l[tid] = bout[tid];
    __syncthreads();

    const int ks   = tid >> 7;     // K-split group 0..3
    const int c4   = tid & 127;    // column group
    const int col0 = c4 << 2;      // owns columns col0..col0+3

    for (int t = 0; t < T_STEPS; ++t) {
        const size_t base = ((size_t)t * B_SZ + b0) * H_SZ + j;

        // ---- phase A: STP dynamics, h_post, stage x_t ----
#pragma unroll
        for (int r = 0; r < BTILE; ++r) {
            float hv  = h_lds[r][j];
            float sxv = sxr[r], suv = sur[r];
            float sxn = sxv + a_std * (1.0f - sxv) - 0.01f * suv * sxv * hv;
            float sun = suv + a_stf * (Uj - suv)   + 0.01f * Uj * (1.0f - suv) * hv;
            sxn = fminf(fmaxf(sxn, 0.0f), 1.0f);
            sun = fminf(fmaxf(sun, 0.0f), 1.0f);
            sxr[r] = sxn; sur[r] = sun;
            hpT[j][r] = sun * sxn * hv;
            out_sx[base + (size_t)r * H_SZ] = sxn;
            out_su[base + (size_t)r * H_SZ] = sun;
        }
        if (tid < BTILE * NIN_SZ) {
            int r = tid >> 6, k = tid & 63;
            xtT[k][r] = x[((size_t)t * B_SZ + b0 + r) * NIN_SZ + k];
        }
        __syncthreads();

        // ---- phase B: recurrent matvec + input projection (4-way K-split) ----
        float acc[BTILE][4];
#pragma unroll
        for (int r = 0; r < BTILE; ++r)
#pragma unroll
            for (int c = 0; c < 4; ++c) acc[r][c] = 0.0f;

        {
            const float*  wr = wrnn + (size_t)(ks * 128) * H_SZ + col0;
            const float4* hp = (const float4*)&hpT[ks * 128][0];
#pragma unroll 4
            for (int k = 0; k < 128; ++k) {
                float4 w  = *(const float4*)(wr + (size_t)k * H_SZ);
                float4 h4 = hp[k];
                FMA16(h4, w)
            }
        }
        {
            const float*  wi = win + (size_t)(ks * 16) * H_SZ + col0;
            const float4* xp = (const float4*)&xtT[ks * 16][0];
#pragma unroll 4
            for (int k = 0; k < 16; ++k) {
                float4 w  = *(const float4*)(wi + (size_t)k * H_SZ);
                float4 h4 = xp[k];
                FMA16(h4, w)
            }
        }
#pragma unroll
        for (int r = 0; r < BTILE; ++r)
            *(float4*)&cbuf[ks][r][col0] =
                make_float4(acc[r][0], acc[r][1], acc[r][2], acc[r][3]);
        __syncthreads();

        // ---- phase C: combine partials, membrane update ----
#pragma unroll
        for (int r = 0; r < BTILE; ++r) {
            float c = cbuf[0][r][j] + cbuf[1][r][j] + cbuf[2][r][j] + cbuf[3][r][j]
                    + brnn_l[j];
            float hv = h_lds[r][j];
            float hn = 0.9f * hv + 0.1f * c + noise[base + (size_t)r * H_SZ];
            hn = fmaxf(hn, 0.0f);
            h_lds[r][j] = hn;
            out_h[base + (size_t)r * H_SZ] = hn;
        }
        __syncthreads();

        // ---- phase D: logits = h_new @ Wout + b_out ----
        {
            const int g = tid >> 4;            // 0..31 row-of-j group
            float part[BTILE] = {0.f, 0.f, 0.f, 0.f};
#pragma unroll
            for (int i = 0; i < 16; ++i) {
                // flat = (g+32i)*16 + (tid&15) = tid + 512*i  -> coalesced
                float w  = wout[(size_t)512 * i + tid];
                int   jj = g + 32 * i;
#pragma unroll
                for (int r = 0; r < BTILE; ++r)
                    part[r] = fmaf(h_lds[r][jj], w, part[r]);
            }
#pragma unroll
            for (int r = 0; r < BTILE; ++r) {
                part[r] += __shfl_xor(part[r], 16);
                part[r] += __shfl_xor(part[r], 32);
            }
            const int lane = tid & 63;
            const int wv   = tid >> 6;
            if (lane < 16) {
#pragma unroll
                for (int r = 0; r < BTILE; ++r) pbuf[wv][r][lane] = part[r];
            }
            __syncthreads();
            if (tid < 64) {
                int r = tid >> 4, o = tid & 15;
                float s = bout_l[o];
#pragma unroll
                for (int w = 0; w < 8; ++w) s += pbuf[w][r][o];
                out_logits[((size_t)t * B_SZ + b0 + r) * NOUT_SZ + o] = s;
            }
        }
        // No trailing barrier needed: next-step writes to hpT/cbuf/pbuf are
        // separated from this step's reads by the A/B/C barriers.
    }
}

extern "C" void kernel_launch(void* const* d_in, const int* in_sizes, int n_in,
                              void* d_out, int out_size, void* d_ws, size_t ws_size,
                              hipStream_t stream) {
    const float* x     = (const float*)d_in[0];
    const float* noise = (const float*)d_in[1];
    const float* W_in  = (const float*)d_in[2];
    const float* W_rnn = (const float*)d_in[3];
    const float* b_rnn = (const float*)d_in[4];
    const float* W_out = (const float*)d_in[5];
    const float* b_out = (const float*)d_in[6];

    float* ws       = (float*)d_ws;
    float* wrnn_eff = ws;
    float* win_eff  = ws + (size_t)H_SZ * H_SZ;
    float* wout_eff = win_eff + (size_t)NIN_SZ * H_SZ;

    float* out_logits = (float*)d_out;
    float* out_h  = out_logits + (size_t)T_STEPS * B_SZ * NOUT_SZ;
    float* out_sx = out_h  + (size_t)T_STEPS * B_SZ * H_SZ;
    float* out_su = out_sx + (size_t)T_STEPS * B_SZ * H_SZ;

    const int total = H_SZ * H_SZ + NIN_SZ * H_SZ + H_SZ * NOUT_SZ;  // 303104
    prep_weights<<<(total + 255) / 256, 256, 0, stream>>>(W_in, W_rnn, W_out, ws);
    biornn_seq<<<NBLK, NTHR, 0, stream>>>(x, noise, wrnn_eff, win_eff, wout_eff,
                                          b_rnn, b_out,
                                          out_logits, out_h, out_sx, out_su);
}